// Round 8
// baseline (592.701 us; speedup 1.0000x reference)
//
#include <hip/hip_runtime.h>
#include <hip/hip_bf16.h>

typedef __bf16 bf16;
typedef bf16 bf16x8 __attribute__((ext_vector_type(8)));
typedef bf16 bf16x4 __attribute__((ext_vector_type(4)));
typedef float f32x4 __attribute__((ext_vector_type(4)));
typedef float f32x16 __attribute__((ext_vector_type(16)));
typedef unsigned int uint2v __attribute__((ext_vector_type(2)));

#define MFMA16(a, b, c) __builtin_amdgcn_mfma_f32_16x16x32_bf16(a, b, c, 0, 0, 0)
#define MFMA32(a, b, c) __builtin_amdgcn_mfma_f32_32x32x16_bf16(a, b, c, 0, 0, 0)

constexpr int Bn = 4, Sn = 2048, Dn = 1024, Hn = 16, HDn = 64;
constexpr int Mn = Bn * Sn;  // 8192
constexpr unsigned GRID = 512;

__device__ __forceinline__ bf16x8 cvt8(float4 a, float4 b) {
  bf16x8 v = {(bf16)a.x, (bf16)a.y, (bf16)a.z, (bf16)a.w,
              (bf16)b.x, (bf16)b.y, (bf16)b.z, (bf16)b.w};
  return v;
}

__device__ __forceinline__ void load_lds16(const bf16* g, bf16* l) {
  __builtin_amdgcn_global_load_lds(
      (const __attribute__((address_space(1))) void*)g,
      (__attribute__((address_space(3))) void*)l, 16, 0, 0);
}

__device__ __forceinline__ unsigned cvt_pk_bf16(float lo, float hi) {
  unsigned r;
  asm("v_cvt_pk_bf16_f32 %0, %1, %2" : "=v"(r) : "v"(lo), "v"(hi));
  return r;
}

// Manual grid barrier (normal launch; graph-capture safe).
// Release: __syncthreads (all waves' stores in L2) + __threadfence (waitcnt +
// L2 writeback to IC). Arrive/poll: device-scope RMWs (performed at the
// coherence point -> immune to XCD-L2 staleness). Acquire: __threadfence
// AFTER completion (invalidates this XCD's L1/L2 clean-stale lines -- the
// reader-side fence round 7 was missing; kills the ctx/Xb alias hazard).
// Counter zeroed per replay by a hipMemsetAsync graph node. Bounded spin so
// a broken co-residency assumption produces a wrong answer, never a hang.
__device__ __forceinline__ void grid_barrier(unsigned* ctr) {
  __syncthreads();
  __threadfence();
  if (threadIdx.x == 0) {
    atomicAdd(ctr, 1u);
    unsigned tries = 0;
    while (atomicAdd(ctr, 0u) < GRID) {
      __builtin_amdgcn_s_sleep(32);
      if (++tries > 100000000u) break;
    }
  }
  __syncthreads();
  __threadfence();
}

// ===== single fused kernel, manual grid barriers ===========================
// Round-6 accounting: 4 kernels sum to ~174-190us GPU time, dur_us=240.7 ->
// ~50-65us inter-dispatch overhead. Phase bodies are byte-identical to the
// proven round-6 kernels. Co-residency: launch_bounds(256,2) caps VGPR<=256
// -> >=2 blocks/CU; LDS 48KB -> 3/CU; capacity >= 512 = grid.
__global__ __launch_bounds__(256, 2) void k_fused(
    const float* __restrict__ hidden, const float* __restrict__ w_attn,
    const float* __restrict__ w_proj, const float* __restrict__ b_attn,
    const float* __restrict__ b_proj, bf16* __restrict__ Xb,
    bf16* __restrict__ wattnT, bf16* __restrict__ wprojT,
    bf16* __restrict__ Qb, bf16* __restrict__ Kb, bf16* __restrict__ Vt,
    bf16* __restrict__ ctx, float* __restrict__ out, unsigned* ctrs) {
  __shared__ alignas(16) unsigned char smem[49152];
  const int b = blockIdx.x;  // 0..511
  const int tid = threadIdx.x;
  const int w = tid >> 6, lane = tid & 63, l15 = lane & 15, quad = lane >> 4;

  // ---------------- phase 1: prep (cvt + weight transposes) ----------------
  {
    bf16(*t)[72] = (bf16(*)[72])smem;
    for (int u = b; u < 5120; u += 512) {
      if (u < 4096) {  // cvt hidden f32 -> bf16
        int i = u * 256 + tid;
        const float4* p = (const float4*)hidden + (size_t)i * 2;
        float4 a = p[0], bb = p[1];
        *((bf16x8*)Xb + i) = cvt8(a, bb);
      } else {
        const float* in;
        bf16* outp;
        int K = 1024, N, n0, k0;
        if (u < 4864) {
          int idx = u - 4096;  // 48 x 16
          in = w_attn; outp = wattnT; N = 3072;
          n0 = (idx % 48) * 64; k0 = (idx / 48) * 64;
        } else {
          int idx = u - 4864;  // 16 x 16
          in = w_proj; outp = wprojT; N = 1024;
          n0 = (idx % 16) * 64; k0 = (idx / 16) * 64;
        }
        {
          int row = tid >> 2;
          int c16 = (tid & 3) * 16;
          const float* src = in + (size_t)(k0 + row) * N + n0 + c16;
          float4 f0 = ((const float4*)src)[0];
          float4 f1 = ((const float4*)src)[1];
          float4 f2 = ((const float4*)src)[2];
          float4 f3 = ((const float4*)src)[3];
          *(bf16x8*)&t[row][c16] = cvt8(f0, f1);
          *(bf16x8*)&t[row][c16 + 8] = cvt8(f2, f3);
        }
        __syncthreads();
#pragma unroll
        for (int i = 0; i < 2; i++) {
          int c = tid + i * 256;
          int nrow = c >> 3, kcol8 = (c & 7) * 8;
          bf16x8 v;
#pragma unroll
          for (int j = 0; j < 8; j++) v[j] = t[kcol8 + j][nrow];
          *(bf16x8*)(outp + (size_t)(n0 + nrow) * K + k0 + kcol8) = v;
        }
        __syncthreads();  // guard t reuse across strided units
      }
    }
  }
  grid_barrier(ctrs + 0);

  // ---------------- phase 2: QKV GEMM (m97 core, XCD-banded) ---------------
  {
    bf16* la = (bf16*)smem;             // 128*32 elems
    bf16* lb = (bf16*)(smem + 8192);
    const int wm = w >> 1, wn = w & 1;
    const int lrow = lane >> 2, lcol = (lane & 3) * 8;
    for (int u = b; u < 1536; u += 512) {
      const int xcd = u & 7, idx = u >> 3;
      const int by = xcd * 8 + idx / 24;
      const int bx = idx % 24;
      const int m0 = by * 128, n0 = bx * 128;

      f32x4 acc[4][4];
#pragma unroll
      for (int i = 0; i < 4; i++)
#pragma unroll
        for (int j = 0; j < 4; j++) acc[i][j] = f32x4{0.f, 0.f, 0.f, 0.f};

      for (int k0 = 0; k0 < 1024; k0 += 32) {
        __syncthreads();
        load_lds16(Xb + (size_t)(m0 + w * 16 + lrow) * 1024 + k0 + lcol, &la[w * 512]);
        load_lds16(Xb + (size_t)(m0 + 64 + w * 16 + lrow) * 1024 + k0 + lcol, &la[(w + 4) * 512]);
        load_lds16(wattnT + (size_t)(n0 + w * 16 + lrow) * 1024 + k0 + lcol, &lb[w * 512]);
        load_lds16(wattnT + (size_t)(n0 + 64 + w * 16 + lrow) * 1024 + k0 + lcol, &lb[(w + 4) * 512]);
        __syncthreads();
        bf16x8 af[4], bfr[4];
#pragma unroll
        for (int i = 0; i < 4; i++)
          af[i] = *(const bf16x8*)&la[(wm * 64 + i * 16 + l15) * 32 + quad * 8];
#pragma unroll
        for (int j = 0; j < 4; j++)
          bfr[j] = *(const bf16x8*)&lb[(wn * 64 + j * 16 + l15) * 32 + quad * 8];
#pragma unroll
        for (int i = 0; i < 4; i++)
#pragma unroll
          for (int j = 0; j < 4; j++) acc[i][j] = MFMA16(af[i], bfr[j], acc[i][j]);
      }

#pragma unroll
      for (int j = 0; j < 4; j++) {
        int ng = n0 + wn * 64 + j * 16 + l15;
        float bs = b_attn[ng];
        int which = ng >> 10;
        int nloc = ng & 1023, hh = nloc >> 6, hd = nloc & 63;
#pragma unroll
        for (int i = 0; i < 4; i++) {
          int mg0 = m0 + wm * 64 + i * 16 + quad * 4;
          int bb = mg0 >> 11, ss = mg0 & 2047;
          if (which == 2) {
            bf16x4 v;
#pragma unroll
            for (int r = 0; r < 4; r++) v[r] = (bf16)(acc[i][j][r] + bs);
            *(bf16x4*)&Vt[((size_t)(bb * Hn + hh) * HDn + hd) * Sn + ss] = v;
          } else {
            bf16* dst = which ? Kb : Qb;
#pragma unroll
            for (int r = 0; r < 4; r++)
              dst[((size_t)(bb * Hn + hh) * Sn + ss + r) * HDn + hd] =
                  (bf16)(acc[i][j][r] + bs);
          }
        }
      }
      __syncthreads();  // guard la/lb reuse across strided units
    }
  }
  grid_barrier(ctrs + 1);

  // ---------------- phase 3: attention (tri-buffer counted vmcnt) ----------
  {
    bf16* kl = (bf16*)smem;              // 3 x 4096 elems
    bf16* vl = (bf16*)(smem + 24576);    // 3 x 4096 elems
    const int l31 = lane & 31, hi = lane >> 5;
    const int r0 = tid >> 3, s0 = tid & 7;
    const int ksw = (s0 ^ (r0 & 7)) << 3;
    const int sw7 = l31 & 7;

#pragma unroll 1
    for (int half = 0; half < 2; ++half) {
      const int u = half ? (1023 - b) : b;
      const int bh = u & 63;
      const int qt = 15 - (u >> 6);  // half0: 15..8, half1: 7..0 (sum 34 tiles)
      const int bb = bh >> 4, hh = bh & 15;
      const size_t base = (size_t)bh * Sn * HDn;
      const int q0 = qt * 128 + w * 32;
      const int nt = 2 * qt + 2;

      const bf16* Krow = Kb + base + (size_t)r0 * 64 + ksw;
      const bf16* Vrow0 = Vt + ((size_t)bh * 64 + r0) * Sn + ksw;
      const bf16* Vrow1 = Vt + ((size_t)bh * 64 + r0 + 32) * Sn + ksw;

      bf16x8 qf[4];
#pragma unroll
      for (int c = 0; c < 4; c++) {
        bf16x8 v = *(const bf16x8*)(Qb + base + (size_t)(q0 + l31) * 64 + c * 16 + hi * 8);
#pragma unroll
        for (int e = 0; e < 8; e++) v[e] = (bf16)((float)v[e] * 0.125f);
        qf[c] = v;
      }

      f32x16 o0, o1;
#pragma unroll
      for (int e = 0; e < 16; e++) { o0[e] = 0.f; o1[e] = 0.f; }
      float dsum = 0.f;

#define STAGE(t_, bf_)                                                        \
  {                                                                           \
    const int kb_ = (t_) * 64;                                                \
    load_lds16(Krow + (size_t)kb_ * 64, kl + (bf_) * 4096 + w * 512);         \
    load_lds16(Krow + (size_t)(kb_ + 32) * 64,                                \
               kl + (bf_) * 4096 + 2048 + w * 512);                           \
    load_lds16(Vrow0 + kb_, vl + (bf_) * 4096 + w * 512);                     \
    load_lds16(Vrow1 + kb_, vl + (bf_) * 4096 + 2048 + w * 512);              \
  }

      STAGE(0, 0)
      STAGE(1, 1)  // nt >= 2 always

      int cb = 0, sb = 2;
      for (int t = 0; t < nt; ++t) {
        if (t == nt - 1) asm volatile("s_waitcnt vmcnt(0)" ::: "memory");
        else             asm volatile("s_waitcnt vmcnt(4)" ::: "memory");
        __builtin_amdgcn_s_barrier();
        if (t + 2 < nt) STAGE(t + 2, sb)
        const int kb = t * 64;
        if (kb <= q0 + 31) {
          const bf16* klc = kl + cb * 4096;
          const bf16* vlc = vl + cb * 4096;
#pragma unroll
          for (int sub = 0; sub < 2; sub++) {
            const int ks0 = kb + sub * 32;
            if (ks0 > q0 + 31) break;
            f32x16 st;
#pragma unroll
            for (int e = 0; e < 16; e++) st[e] = 0.f;
#pragma unroll
            for (int c = 0; c < 4; c++) {
              const int row = sub * 32 + l31;
              bf16x8 kf = *(const bf16x8*)&klc[row * 64 + (((2 * c + hi) ^ sw7) << 3)];
              st = MFMA32(kf, qf[c], st);
            }
            if (ks0 == q0) {
#pragma unroll
              for (int r = 0; r < 16; r++) {
                int krel = (r & 3) + 8 * (r >> 2) + 4 * hi;
                if (krel > l31) st[r] = -1e30f;
              }
            }
#pragma unroll
            for (int r = 0; r < 16; r++) {
              st[r] = __expf(st[r]);
              dsum += st[r];
            }
#pragma unroll
            for (int c2 = 0; c2 < 2; c2++) {
              unsigned wa0 = cvt_pk_bf16(st[8 * c2 + 0], st[8 * c2 + 1]);
              unsigned wa1 = cvt_pk_bf16(st[8 * c2 + 2], st[8 * c2 + 3]);
              unsigned wb0 = cvt_pk_bf16(st[8 * c2 + 4], st[8 * c2 + 5]);
              unsigned wb1 = cvt_pk_bf16(st[8 * c2 + 6], st[8 * c2 + 7]);
              unsigned pw0, pw1, pw2, pw3;
#if __has_builtin(__builtin_amdgcn_permlane32_swap)
              uint2v sw0 = __builtin_amdgcn_permlane32_swap(wa0, wb0, false, false);
              uint2v sw1 = __builtin_amdgcn_permlane32_swap(wa1, wb1, false, false);
              pw0 = sw0.x; pw1 = sw1.x; pw2 = sw0.y; pw3 = sw1.y;
#else
              unsigned xa0 = __shfl_xor((int)wa0, 32, 64), xb0 = __shfl_xor((int)wb0, 32, 64);
              unsigned xa1 = __shfl_xor((int)wa1, 32, 64), xb1 = __shfl_xor((int)wb1, 32, 64);
              pw0 = hi ? xb0 : wa0; pw1 = hi ? xb1 : wa1;
              pw2 = hi ? wb0 : xa0; pw3 = hi ? wb1 : xa1;
#endif
              union { unsigned uu[4]; bf16x8 v; } pb;
              pb.uu[0] = pw0; pb.uu[1] = pw1; pb.uu[2] = pw2; pb.uu[3] = pw3;
              const int vs = sub * 4 + 2 * c2;
              bf16x8 vf0 = *(const bf16x8*)&vlc[l31 * 64 + (((vs + hi) ^ sw7) << 3)];
              o0 = MFMA32(vf0, pb.v, o0);
              bf16x8 vf1 = *(const bf16x8*)&vlc[(32 + l31) * 64 + (((vs + hi) ^ sw7) << 3)];
              o1 = MFMA32(vf1, pb.v, o1);
            }
          }
        }
        cb = (cb == 2) ? 0 : cb + 1;
        sb = (sb == 2) ? 0 : sb + 1;
      }
#undef STAGE

      float tot = dsum + __shfl_xor(dsum, 32, 64);
      float inv = 1.f / fmaxf(tot, 1e-20f);
      size_t ob = ((size_t)(bb * Sn + q0 + l31)) * Dn + hh * HDn + hi * 4;
#pragma unroll
      for (int g = 0; g < 4; g++) {
        bf16x4 v0, v1;
#pragma unroll
        for (int r = 0; r < 4; r++) {
          v0[r] = (bf16)(o0[4 * g + r] * inv);
          v1[r] = (bf16)(o1[4 * g + r] * inv);
        }
        *(bf16x4*)&ctx[ob + g * 8] = v0;
        *(bf16x4*)&ctx[ob + 32 + g * 8] = v1;
      }
      __syncthreads();  // guard kl/vl reuse between halves
    }
  }
  grid_barrier(ctrs + 2);

  // ---------------- phase 4: proj GEMM ------------------------------------
  {
    bf16* la = (bf16*)smem;
    bf16* lb = (bf16*)(smem + 8192);
    const int wm = w >> 1, wn = w & 1;
    const int lrow = lane >> 2, lcol = (lane & 3) * 8;
    const int xcd = b & 7, idx = b >> 3;
    const int by = xcd * 8 + (idx >> 3);
    const int bx = idx & 7;
    const int m0 = by * 128, n0 = bx * 128;

    f32x4 acc[4][4];
#pragma unroll
    for (int i = 0; i < 4; i++)
#pragma unroll
      for (int j = 0; j < 4; j++) acc[i][j] = f32x4{0.f, 0.f, 0.f, 0.f};

    for (int k0 = 0; k0 < 1024; k0 += 32) {
      __syncthreads();
      load_lds16(ctx + (size_t)(m0 + w * 16 + lrow) * 1024 + k0 + lcol, &la[w * 512]);
      load_lds16(ctx + (size_t)(m0 + 64 + w * 16 + lrow) * 1024 + k0 + lcol, &la[(w + 4) * 512]);
      load_lds16(wprojT + (size_t)(n0 + w * 16 + lrow) * 1024 + k0 + lcol, &lb[w * 512]);
      load_lds16(wprojT + (size_t)(n0 + 64 + w * 16 + lrow) * 1024 + k0 + lcol, &lb[(w + 4) * 512]);
      __syncthreads();
      bf16x8 af[4], bfr[4];
#pragma unroll
      for (int i = 0; i < 4; i++)
        af[i] = *(const bf16x8*)&la[(wm * 64 + i * 16 + l15) * 32 + quad * 8];
#pragma unroll
      for (int j = 0; j < 4; j++)
        bfr[j] = *(const bf16x8*)&lb[(wn * 64 + j * 16 + l15) * 32 + quad * 8];
#pragma unroll
      for (int i = 0; i < 4; i++)
#pragma unroll
        for (int j = 0; j < 4; j++) acc[i][j] = MFMA16(af[i], bfr[j], acc[i][j]);
    }

#pragma unroll
    for (int j = 0; j < 4; j++) {
      int ng = n0 + wn * 64 + j * 16 + l15;
      float bs = b_proj[ng];
#pragma unroll
      for (int i = 0; i < 4; i++) {
        int mg0 = m0 + wm * 64 + i * 16 + quad * 4;
#pragma unroll
        for (int r = 0; r < 4; r++)
          out[(size_t)(mg0 + r) * 1024 + ng] = acc[i][j][r] + bs;
      }
    }
  }
}

extern "C" void kernel_launch(void* const* d_in, const int* in_sizes, int n_in,
                              void* d_out, int out_size, void* d_ws, size_t ws_size,
                              hipStream_t stream) {
  const float* hidden = (const float*)d_in[0];   // [8192,1024] f32
  const float* w_attn = (const float*)d_in[1];   // [1024,3072] f32
  const float* b_attn = (const float*)d_in[2];   // [3072] f32
  const float* w_proj = (const float*)d_in[3];   // [1024,1024] f32
  const float* b_proj = (const float*)d_in[4];   // [1024] f32
  float* out = (float*)d_out;                    // [8192,1024] f32

  bf16* ws = (bf16*)d_ws;
  const size_t QKV_ELEMS = (size_t)Bn * Hn * Sn * HDn;  // 8388608
  bf16* Qb = ws;
  bf16* Kb = Qb + QKV_ELEMS;
  bf16* Vt = Kb + QKV_ELEMS;
  bf16* ctx = Vt + QKV_ELEMS;     // doubles as Xb (dead before attn writes ctx)
  bf16* Xb = ctx;
  bf16* wattnT = ctx + (size_t)Mn * Dn;
  bf16* wprojT = wattnT + (size_t)Dn * 3 * Dn;
  unsigned* ctrs = (unsigned*)(wprojT + (size_t)Dn * Dn);  // 3 barrier counters

  hipMemsetAsync(ctrs, 0, 3 * sizeof(unsigned), stream);
  k_fused<<<dim3(GRID), dim3(256), 0, stream>>>(
      hidden, w_attn, w_proj, b_attn, b_proj, Xb, wattnT, wprojT, Qb, Kb, Vt,
      ctx, out, ctrs);
}

// Round 9
// 245.513 us; speedup vs baseline: 2.4141x; 2.4141x over previous
//
#include <hip/hip_runtime.h>
#include <hip/hip_bf16.h>

typedef __bf16 bf16;
typedef bf16 bf16x8 __attribute__((ext_vector_type(8)));
typedef bf16 bf16x4 __attribute__((ext_vector_type(4)));
typedef float f32x4 __attribute__((ext_vector_type(4)));
typedef float f32x16 __attribute__((ext_vector_type(16)));
typedef unsigned int uint2v __attribute__((ext_vector_type(2)));

#define MFMA16(a, b, c) __builtin_amdgcn_mfma_f32_16x16x32_bf16(a, b, c, 0, 0, 0)
#define MFMA32(a, b, c) __builtin_amdgcn_mfma_f32_32x32x16_bf16(a, b, c, 0, 0, 0)

constexpr int Bn = 4, Sn = 2048, Dn = 1024, Hn = 16, HDn = 64;
constexpr int Mn = Bn * Sn;  // 8192

__device__ __forceinline__ bf16x8 cvt8(float4 a, float4 b) {
  bf16x8 v = {(bf16)a.x, (bf16)a.y, (bf16)a.z, (bf16)a.w,
              (bf16)b.x, (bf16)b.y, (bf16)b.z, (bf16)b.w};
  return v;
}

// async global->LDS, 16B per lane; LDS dest is wave-uniform base + lane*16
__device__ __forceinline__ void load_lds16(const bf16* g, bf16* l) {
  __builtin_amdgcn_global_load_lds(
      (const __attribute__((address_space(1))) void*)g,
      (__attribute__((address_space(3))) void*)l, 16, 0, 0);
}

__device__ __forceinline__ unsigned cvt_pk_bf16(float lo, float hi) {
  unsigned r;
  asm("v_cvt_pk_bf16_f32 %0, %1, %2" : "=v"(r) : "v"(lo), "v"(hi));
  return r;
}

// ------- merged preprocessing: cvt hidden + transpose both weights ----------
__global__ __launch_bounds__(256) void k_prep(const float* __restrict__ hidden,
                                              const float* __restrict__ w_attn,
                                              const float* __restrict__ w_proj,
                                              bf16* __restrict__ Xb,
                                              bf16* __restrict__ wattnT,
                                              bf16* __restrict__ wprojT) {
  __shared__ alignas(16) bf16 t[64][72];
  const int bx = blockIdx.x;
  const int tid = threadIdx.x;
  if (bx < 4096) {  // ---- cvt ----
    int i = bx * 256 + tid;
    const float4* p = (const float4*)hidden + (size_t)i * 2;
    float4 a = p[0], b = p[1];
    *((bf16x8*)Xb + i) = cvt8(a, b);
    return;
  }
  // ---- transpose+cvt ----
  const float* in;
  bf16* out;
  int K = 1024, N, n0, k0;
  if (bx < 4864) {
    int idx = bx - 4096;  // 48 x 16
    in = w_attn; out = wattnT; N = 3072;
    n0 = (idx % 48) * 64; k0 = (idx / 48) * 64;
  } else {
    int idx = bx - 4864;  // 16 x 16
    in = w_proj; out = wprojT; N = 1024;
    n0 = (idx % 16) * 64; k0 = (idx / 16) * 64;
  }
  {
    int row = tid >> 2;
    int c16 = (tid & 3) * 16;
    const float* src = in + (size_t)(k0 + row) * N + n0 + c16;
    float4 f0 = ((const float4*)src)[0];
    float4 f1 = ((const float4*)src)[1];
    float4 f2 = ((const float4*)src)[2];
    float4 f3 = ((const float4*)src)[3];
    *(bf16x8*)&t[row][c16] = cvt8(f0, f1);
    *(bf16x8*)&t[row][c16 + 8] = cvt8(f2, f3);
  }
  __syncthreads();
#pragma unroll
  for (int i = 0; i < 2; i++) {
    int c = tid + i * 256;
    int nrow = c >> 3, kcol8 = (c & 7) * 8;
    bf16x8 v;
#pragma unroll
    for (int j = 0; j < 8; j++) v[j] = t[kcol8 + j][nrow];
    *(bf16x8*)(out + (size_t)(n0 + nrow) * K + k0 + kcol8) = v;
  }
}

// ======= m97-style 128x128 GEMM core (proven round-3 form, 73.5us) =========
// History: counted-vmcnt pipelines (r4/r5), 8-phase 256^2 (r1), XCD swizzle
// (r6, -20% FETCH but +2.5% time: L3-fit regime), and full fusion (r7/r8,
// cold-cache + occupancy collapse) ALL lost to this plain 2-barrier loop at
// this shape. Keep it.

// ------- QKV GEMM -> Q[B,H,S,HD], K[B,H,S,HD], V^T[B,H,HD,S] (all bf16) ------
__global__ __launch_bounds__(256) void k_gemm_qkv(const bf16* __restrict__ A,
                                                  const bf16* __restrict__ BT,
                                                  const float* __restrict__ bias,
                                                  bf16* __restrict__ Qo,
                                                  bf16* __restrict__ Ko,
                                                  bf16* __restrict__ Vt) {
  __shared__ alignas(16) bf16 la[128 * 32];
  __shared__ alignas(16) bf16 lb[128 * 32];
  const int tid = threadIdx.x;
  const int w = tid >> 6, lane = tid & 63, l15 = lane & 15, quad = lane >> 4;
  const int wm = w >> 1, wn = w & 1;
  const int m0 = blockIdx.y * 128, n0 = blockIdx.x * 128;
  const int lrow = lane >> 2, lcol = (lane & 3) * 8;

  f32x4 acc[4][4];
#pragma unroll
  for (int i = 0; i < 4; i++)
#pragma unroll
    for (int j = 0; j < 4; j++) acc[i][j] = f32x4{0.f, 0.f, 0.f, 0.f};

  for (int k0 = 0; k0 < 1024; k0 += 32) {
    __syncthreads();
    load_lds16(A + (size_t)(m0 + w * 16 + lrow) * 1024 + k0 + lcol, &la[w * 512]);
    load_lds16(A + (size_t)(m0 + 64 + w * 16 + lrow) * 1024 + k0 + lcol, &la[(w + 4) * 512]);
    load_lds16(BT + (size_t)(n0 + w * 16 + lrow) * 1024 + k0 + lcol, &lb[w * 512]);
    load_lds16(BT + (size_t)(n0 + 64 + w * 16 + lrow) * 1024 + k0 + lcol, &lb[(w + 4) * 512]);
    __syncthreads();
    bf16x8 af[4], bfr[4];
#pragma unroll
    for (int i = 0; i < 4; i++)
      af[i] = *(const bf16x8*)&la[(wm * 64 + i * 16 + l15) * 32 + quad * 8];
#pragma unroll
    for (int j = 0; j < 4; j++)
      bfr[j] = *(const bf16x8*)&lb[(wn * 64 + j * 16 + l15) * 32 + quad * 8];
#pragma unroll
    for (int i = 0; i < 4; i++)
#pragma unroll
      for (int j = 0; j < 4; j++) acc[i][j] = MFMA16(af[i], bfr[j], acc[i][j]);
  }

#pragma unroll
  for (int j = 0; j < 4; j++) {
    int ng = n0 + wn * 64 + j * 16 + l15;
    float bs = bias[ng];
    int which = ng >> 10;  // 0=Q 1=K 2=V (uniform per 16-col subtile)
    int nloc = ng & 1023, hh = nloc >> 6, hd = nloc & 63;
#pragma unroll
    for (int i = 0; i < 4; i++) {
      int mg0 = m0 + wm * 64 + i * 16 + quad * 4;
      int bb = mg0 >> 11, ss = mg0 & 2047;
      if (which == 2) {
        bf16x4 v;
#pragma unroll
        for (int r = 0; r < 4; r++) v[r] = (bf16)(acc[i][j][r] + bs);
        *(bf16x4*)&Vt[((size_t)(bb * Hn + hh) * HDn + hd) * Sn + ss] = v;
      } else {
        bf16* dst = which ? Ko : Qo;
#pragma unroll
        for (int r = 0; r < 4; r++)
          dst[((size_t)(bb * Hn + hh) * Sn + ss + r) * HDn + hd] =
              (bf16)(acc[i][j][r] + bs);
      }
    }
  }
}

// ------- proj GEMM: ctx bf16 @ wprojT + bias -> out f32 -------
__global__ __launch_bounds__(256) void k_gemm_proj(const bf16* __restrict__ A,
                                                   const bf16* __restrict__ BT,
                                                   const float* __restrict__ bias,
                                                   float* __restrict__ out) {
  __shared__ alignas(16) bf16 la[128 * 32];
  __shared__ alignas(16) bf16 lb[128 * 32];
  const int tid = threadIdx.x;
  const int w = tid >> 6, lane = tid & 63, l15 = lane & 15, quad = lane >> 4;
  const int wm = w >> 1, wn = w & 1;
  const int m0 = blockIdx.y * 128, n0 = blockIdx.x * 128;
  const int lrow = lane >> 2, lcol = (lane & 3) * 8;

  f32x4 acc[4][4];
#pragma unroll
  for (int i = 0; i < 4; i++)
#pragma unroll
    for (int j = 0; j < 4; j++) acc[i][j] = f32x4{0.f, 0.f, 0.f, 0.f};

  for (int k0 = 0; k0 < 1024; k0 += 32) {
    __syncthreads();
    load_lds16(A + (size_t)(m0 + w * 16 + lrow) * 1024 + k0 + lcol, &la[w * 512]);
    load_lds16(A + (size_t)(m0 + 64 + w * 16 + lrow) * 1024 + k0 + lcol, &la[(w + 4) * 512]);
    load_lds16(BT + (size_t)(n0 + w * 16 + lrow) * 1024 + k0 + lcol, &lb[w * 512]);
    load_lds16(BT + (size_t)(n0 + 64 + w * 16 + lrow) * 1024 + k0 + lcol, &lb[(w + 4) * 512]);
    __syncthreads();
    bf16x8 af[4], bfr[4];
#pragma unroll
    for (int i = 0; i < 4; i++)
      af[i] = *(const bf16x8*)&la[(wm * 64 + i * 16 + l15) * 32 + quad * 8];
#pragma unroll
    for (int j = 0; j < 4; j++)
      bfr[j] = *(const bf16x8*)&lb[(wn * 64 + j * 16 + l15) * 32 + quad * 8];
#pragma unroll
    for (int i = 0; i < 4; i++)
#pragma unroll
      for (int j = 0; j < 4; j++) acc[i][j] = MFMA16(af[i], bfr[j], acc[i][j]);
  }

#pragma unroll
  for (int j = 0; j < 4; j++) {
    int ng = n0 + wn * 64 + j * 16 + l15;
    float bs = bias[ng];
#pragma unroll
    for (int i = 0; i < 4; i++) {
      int mg0 = m0 + wm * 64 + i * 16 + quad * 4;
#pragma unroll
      for (int r = 0; r < 4; r++)
        out[(size_t)(mg0 + r) * 1024 + ng] = acc[i][j][r] + bs;
    }
  }
}

// ------- flash attention, 32x32 swapped-QK^T, in-register softmax ----------
// Round-9 change: LDS 48KB -> 40KB (K triple-buffered, V double-buffered) so
// occupancy rises 3 -> 4 blocks/CU and ALL 1024 blocks are co-resident in a
// single dispatch round (was a ragged 1.33-round schedule). Asymmetric
// counted-vmcnt pipeline, per-wave queue age order at iter t's wait is
// [K(t)(2) V(t)(2) K(t+1)(2)]: vmcnt(2) drains exactly K(t),V(t) and leaves
// K(t+1) in flight (V covered 1 iter, K 2 iters). Within-iter issue order
// V(t+1) THEN K(t+2) preserves that invariant. Stages are issued after the
// barrier into buffers freed at t-1 (same race argument as round 3).
__global__ __launch_bounds__(256) void k_attn(const bf16* __restrict__ Q,
                                              const bf16* __restrict__ Kv,
                                              const bf16* __restrict__ Vtg,
                                              bf16* __restrict__ ctx) {
  __shared__ alignas(16) bf16 kl[3][64 * 64];  // 24KB
  __shared__ alignas(16) bf16 vl[2][64 * 64];  // 16KB  (total 40KB -> 4/CU)

  const int bh = blockIdx.x;
  const int qt = 15 - blockIdx.y;  // longest blocks launch first
  const int bb = bh >> 4, hh = bh & 15;
  const int tid = threadIdx.x;
  const int w = tid >> 6, lane = tid & 63, l31 = lane & 31, hi = lane >> 5;
  const size_t base = (size_t)bh * Sn * HDn;
  const int q0 = qt * 128 + w * 32;
  const int nt = 2 * qt + 2;  // 64-key tiles this block consumes (>= 2)

  const int r0 = tid >> 3, s0 = tid & 7;
  const int ksw = (s0 ^ (r0 & 7)) << 3;
  const bf16* Krow = Kv + base + (size_t)r0 * 64 + ksw;
  const bf16* Vrow0 = Vtg + ((size_t)bh * 64 + r0) * Sn + ksw;
  const bf16* Vrow1 = Vtg + ((size_t)bh * 64 + r0 + 32) * Sn + ksw;
  const int sw7 = l31 & 7;

  bf16x8 qf[4];
#pragma unroll
  for (int c = 0; c < 4; c++) {
    bf16x8 v = *(const bf16x8*)(Q + base + (size_t)(q0 + l31) * 64 + c * 16 + hi * 8);
#pragma unroll
    for (int e = 0; e < 8; e++) v[e] = (bf16)((float)v[e] * 0.125f);
    qf[c] = v;
  }

  f32x16 o0, o1;
#pragma unroll
  for (int e = 0; e < 16; e++) { o0[e] = 0.f; o1[e] = 0.f; }
  float dsum = 0.f;

#define STAGE_K(t_, bf_)                                                   \
  {                                                                        \
    const int kb_ = (t_) * 64;                                             \
    load_lds16(Krow + (size_t)kb_ * 64, &kl[bf_][w * 512]);                \
    load_lds16(Krow + (size_t)(kb_ + 32) * 64, &kl[bf_][2048 + w * 512]);  \
  }
#define STAGE_V(t_, bf_)                                                   \
  {                                                                        \
    const int kb_ = (t_) * 64;                                             \
    load_lds16(Vrow0 + kb_, &vl[bf_][w * 512]);                            \
    load_lds16(Vrow1 + kb_, &vl[bf_][2048 + w * 512]);                     \
  }

  // prologue (issue order matters for vmcnt accounting): K0, V0, K1
  STAGE_K(0, 0)
  STAGE_V(0, 0)
  STAGE_K(1, 1)

  int cb = 0, sbK = 2, vb = 0;  // compute K buf (t%3), K stage buf ((t+2)%3), V buf (t&1)
  for (int t = 0; t < nt; ++t) {
    if (t == nt - 1) asm volatile("s_waitcnt vmcnt(0)" ::: "memory");
    else             asm volatile("s_waitcnt vmcnt(2)" ::: "memory");
    __builtin_amdgcn_s_barrier();  // all waves' K(t),V(t) now in LDS
    if (t + 1 < nt) STAGE_V(t + 1, vb ^ 1)   // vl[(t+1)&1], freed at t-1
    if (t + 2 < nt) STAGE_K(t + 2, sbK)      // kl[(t+2)%3], freed at t-1
    const int kb = t * 64;
    if (kb <= q0 + 31) {
      const bf16* klc = kl[cb];
      const bf16* vlc = vl[vb];
#pragma unroll
      for (int sub = 0; sub < 2; sub++) {
        const int ks0 = kb + sub * 32;
        if (ks0 > q0 + 31) break;
        f32x16 st;
#pragma unroll
        for (int e = 0; e < 16; e++) st[e] = 0.f;
#pragma unroll
        for (int c = 0; c < 4; c++) {
          const int row = sub * 32 + l31;
          bf16x8 kf = *(const bf16x8*)&klc[row * 64 + (((2 * c + hi) ^ sw7) << 3)];
          st = MFMA32(kf, qf[c], st);
        }
        if (ks0 == q0) {
#pragma unroll
          for (int r = 0; r < 16; r++) {
            int krel = (r & 3) + 8 * (r >> 2) + 4 * hi;
            if (krel > l31) st[r] = -1e30f;
          }
        }
#pragma unroll
        for (int r = 0; r < 16; r++) {
          st[r] = __expf(st[r]);
          dsum += st[r];
        }
#pragma unroll
        for (int c2 = 0; c2 < 2; c2++) {
          unsigned wa0 = cvt_pk_bf16(st[8 * c2 + 0], st[8 * c2 + 1]);
          unsigned wa1 = cvt_pk_bf16(st[8 * c2 + 2], st[8 * c2 + 3]);
          unsigned wb0 = cvt_pk_bf16(st[8 * c2 + 4], st[8 * c2 + 5]);
          unsigned wb1 = cvt_pk_bf16(st[8 * c2 + 6], st[8 * c2 + 7]);
          unsigned pw0, pw1, pw2, pw3;
#if __has_builtin(__builtin_amdgcn_permlane32_swap)
          uint2v sw0 = __builtin_amdgcn_permlane32_swap(wa0, wb0, false, false);
          uint2v sw1 = __builtin_amdgcn_permlane32_swap(wa1, wb1, false, false);
          pw0 = sw0.x; pw1 = sw1.x; pw2 = sw0.y; pw3 = sw1.y;
#else
          unsigned xa0 = __shfl_xor((int)wa0, 32, 64), xb0 = __shfl_xor((int)wb0, 32, 64);
          unsigned xa1 = __shfl_xor((int)wa1, 32, 64), xb1 = __shfl_xor((int)wb1, 32, 64);
          pw0 = hi ? xb0 : wa0; pw1 = hi ? xb1 : wa1;
          pw2 = hi ? wb0 : xa0; pw3 = hi ? wb1 : xa1;
#endif
          union { unsigned u[4]; bf16x8 v; } pb;
          pb.u[0] = pw0; pb.u[1] = pw1; pb.u[2] = pw2; pb.u[3] = pw3;
          const int vs = sub * 4 + 2 * c2;
          bf16x8 vf0 = *(const bf16x8*)&vlc[l31 * 64 + (((vs + hi) ^ sw7) << 3)];
          o0 = MFMA32(vf0, pb.v, o0);
          bf16x8 vf1 = *(const bf16x8*)&vlc[(32 + l31) * 64 + (((vs + hi) ^ sw7) << 3)];
          o1 = MFMA32(vf1, pb.v, o1);
        }
      }
    }
    cb = (cb == 2) ? 0 : cb + 1;
    sbK = (sbK == 2) ? 0 : sbK + 1;
    vb ^= 1;
  }
#undef STAGE_K
#undef STAGE_V

  float tot = dsum + __shfl_xor(dsum, 32, 64);
  float inv = 1.f / fmaxf(tot, 1e-20f);
  size_t ob = ((size_t)(bb * Sn + q0 + l31)) * Dn + hh * HDn + hi * 4;
#pragma unroll
  for (int g = 0; g < 4; g++) {
    bf16x4 v0, v1;
#pragma unroll
    for (int r = 0; r < 4; r++) {
      v0[r] = (bf16)(o0[4 * g + r] * inv);
      v1[r] = (bf16)(o1[4 * g + r] * inv);
    }
    *(bf16x4*)&ctx[ob + g * 8] = v0;
    *(bf16x4*)&ctx[ob + 32 + g * 8] = v1;
  }
}

extern "C" void kernel_launch(void* const* d_in, const int* in_sizes, int n_in,
                              void* d_out, int out_size, void* d_ws, size_t ws_size,
                              hipStream_t stream) {
  const float* hidden = (const float*)d_in[0];   // [8192,1024] f32
  const float* w_attn = (const float*)d_in[1];   // [1024,3072] f32
  const float* b_attn = (const float*)d_in[2];   // [3072] f32
  const float* w_proj = (const float*)d_in[3];   // [1024,1024] f32
  const float* b_proj = (const float*)d_in[4];   // [1024] f32
  float* out = (float*)d_out;                    // [8192,1024] f32

  bf16* ws = (bf16*)d_ws;
  const size_t QKV_ELEMS = (size_t)Bn * Hn * Sn * HDn;  // 8388608
  bf16* Qb = ws;
  bf16* Kb = Qb + QKV_ELEMS;
  bf16* Vt = Kb + QKV_ELEMS;
  bf16* ctx = Vt + QKV_ELEMS;     // doubles as Xb (dead before k_attn writes ctx)
  bf16* Xb = ctx;
  bf16* wattnT = ctx + (size_t)Mn * Dn;
  bf16* wprojT = wattnT + (size_t)Dn * 3 * Dn;

  k_prep<<<5120, 256, 0, stream>>>(hidden, w_attn, w_proj, Xb, wattnT, wprojT);
  k_gemm_qkv<<<dim3(24, 64), 256, 0, stream>>>(Xb, wattnT, b_attn, Qb, Kb, Vt);
  k_attn<<<dim3(64, 16), 256, 0, stream>>>(Qb, Kb, Vt, ctx);
  k_gemm_proj<<<dim3(8, 64), 256, 0, stream>>>(ctx, wprojT, b_proj, out);
}